// Round 1
// baseline (1182.461 us; speedup 1.0000x reference)
//
#include <hip/hip_runtime.h>
#include <math.h>
#include <stdint.h>

#define N_NODES 8000
#define N_EDGES 128000
#define NZ 10
#define K 32
#define LDIM 16
#define NB 8
#define NH 32
#define NL 2

// ---------------- edge geometry: Y (sph harm l=0..3), radial basis, rcv histogram ----------------
__global__ __launch_bounds__(256) void k_geom(const float* __restrict__ pos,
                                              const float* __restrict__ shifts,
                                              const int* __restrict__ ei,
                                              float* __restrict__ Y,
                                              float* __restrict__ ef,
                                              int* __restrict__ counts) {
    int e = blockIdx.x * blockDim.x + threadIdx.x;
    if (e >= N_EDGES) return;
    int snd = ei[e];
    int rcv = ei[N_EDGES + e];
    float vx = pos[rcv*3+0] - pos[snd*3+0] + shifts[e*3+0];
    float vy = pos[rcv*3+1] - pos[snd*3+1] + shifts[e*3+1];
    float vz = pos[rcv*3+2] - pos[snd*3+2] + shifts[e*3+2];
    float r2 = vx*vx + vy*vy + vz*vz;
    float r  = sqrtf(fmaxf(r2, 1e-12f));
    float inv = 1.0f / r;
    float x = vx*inv, y = vy*inv, z = vz*inv;

    const float s3    = 1.7320508075688772f;
    const float s5    = 2.2360679774997896f;
    const float s15   = 3.8729833462074170f;
    const float s35_8 = 2.0916500663351885f;   // sqrt(35/8)
    const float s105  = 10.246950765959598f;
    const float s21_8 = 1.6201851746019651f;   // sqrt(21/8)
    const float s7    = 2.6457513110645907f;

    float Yv[16];
    Yv[0]  = 1.0f;
    Yv[1]  = s3*x;  Yv[2] = s3*y;  Yv[3] = s3*z;
    Yv[4]  = s15*x*y;
    Yv[5]  = s15*y*z;
    Yv[6]  = 0.5f*s5*(3.0f*z*z - 1.0f);
    Yv[7]  = s15*x*z;
    Yv[8]  = 0.5f*s15*(x*x - y*y);
    Yv[9]  = s35_8*y*(3.0f*x*x - y*y);
    Yv[10] = s105*x*y*z;
    Yv[11] = s21_8*y*(5.0f*z*z - 1.0f);
    Yv[12] = 0.5f*s7*(5.0f*z*z*z - 3.0f*z);
    Yv[13] = s21_8*x*(5.0f*z*z - 1.0f);
    Yv[14] = 0.5f*s105*z*(x*x - y*y);
    Yv[15] = s35_8*x*(x*x - 3.0f*y*y);
#pragma unroll
    for (int j = 0; j < 16; j++) Y[e*16 + j] = Yv[j];

    // radial: sqrt(2/5)*sin(n*pi*r/5)/r * f_cut(r/5), p=6 poly cutoff
    float uu = fminf(fmaxf(r * 0.2f, 0.0f), 1.0f);
    float u2 = uu*uu;
    float u6 = u2*u2*u2;
    float f  = 1.0f - 28.0f*u6 + 48.0f*u6*uu - 21.0f*u6*u2;
    float c  = 0.632455532033676f * inv * f;   // sqrt(0.4)
    const float PI5 = 3.14159265358979323846f * 0.2f;
#pragma unroll
    for (int n = 1; n <= 8; n++) ef[e*8 + n - 1] = c * sinf((float)n * PI5 * r);

    atomicAdd(&counts[rcv], 1);
}

// ---------------- exclusive scan of counts -> row_ptr (and working copy woff) ----------------
__global__ __launch_bounds__(1024) void k_scan(const int* __restrict__ counts,
                                               int* __restrict__ row_ptr,
                                               int* __restrict__ woff) {
    __shared__ int s[8192];
    int tid = threadIdx.x;
    for (int j = tid; j < 8192; j += 1024) s[j] = (j < N_NODES) ? counts[j] : 0;
    __syncthreads();
    for (int off = 1; off < 8192; off <<= 1) {
        int v[8];
#pragma unroll
        for (int jj = 0; jj < 8; jj++) {
            int idx = tid + jj*1024;
            v[jj] = s[idx] + ((idx >= off) ? s[idx - off] : 0);
        }
        __syncthreads();
#pragma unroll
        for (int jj = 0; jj < 8; jj++) s[tid + jj*1024] = v[jj];
        __syncthreads();
    }
    for (int j = tid; j <= N_NODES; j += 1024) {
        int v = (j == 0) ? 0 : s[j-1];
        row_ptr[j] = v;
        if (j < N_NODES) woff[j] = v;
    }
}

// ---------------- scatter edge ids into CSR order ----------------
__global__ __launch_bounds__(256) void k_scatter(const int* __restrict__ ei,
                                                 int* __restrict__ woff,
                                                 int* __restrict__ perm) {
    int e = blockIdx.x * blockDim.x + threadIdx.x;
    if (e >= N_EDGES) return;
    int r = ei[N_EDGES + e];
    int pp = atomicAdd(&woff[r], 1);
    perm[pp] = e;
}

// ---------------- node embedding: feats[n,k,0] = attrs @ W_embed, rest zero; species idx ----------------
__global__ __launch_bounds__(256) void k_embed(const float* __restrict__ attrs,
                                               const float* __restrict__ We,
                                               float* __restrict__ feats,
                                               int* __restrict__ spec) {
    int i = blockIdx.x * blockDim.x + threadIdx.x;
    if (i >= N_NODES * K) return;
    int n = i >> 5, k = i & 31;
    float a = 0.0f;
#pragma unroll
    for (int z = 0; z < NZ; z++) a += attrs[n*NZ + z] * We[z*K + k];
    float* f = feats + (size_t)n*(K*LDIM) + k*LDIM;
    f[0] = a;
#pragma unroll
    for (int j = 1; j < LDIM; j++) f[j] = 0.0f;
    if (k == 0) {
        int sp = 0; float best = -1.0f;
        for (int z = 0; z < NZ; z++) { float v = attrs[n*NZ + z]; if (v > best) { best = v; sp = z; } }
        spec[n] = sp;
    }
}

// ---------------- per-layer: up = feats @ W_up  (per node) ----------------
__global__ __launch_bounds__(256) void k_up(const float* __restrict__ feats,
                                            const float* __restrict__ Wup,
                                            float* __restrict__ up) {
    __shared__ float lf[512];
    __shared__ float lw[1024];
    int n = blockIdx.x, tid = threadIdx.x;
    const float* f = feats + (size_t)n*512;
    for (int j = tid; j < 512;  j += 256) lf[j] = f[j];
    for (int j = tid; j < 1024; j += 256) lw[j] = Wup[j];
    __syncthreads();
#pragma unroll
    for (int jj = 0; jj < 2; jj++) {
        int idx = tid + jj*256;
        int c = idx >> 4, Lp = idx & 15;
        float a = 0.0f;
#pragma unroll
        for (int k = 0; k < K; k++) a += lf[k*16 + Lp] * lw[k*K + c];
        up[(size_t)n*512 + idx] = a;
    }
}

// ---------------- per-layer aggregation over incident edges (one block per receiving node) ----------------
__global__ __launch_bounds__(256) void k_agg(const float* __restrict__ up,
                                             const float* __restrict__ Y,
                                             const float* __restrict__ ef,
                                             const int* __restrict__ ei,
                                             const int* __restrict__ row_ptr,
                                             const int* __restrict__ perm,
                                             const float* __restrict__ Wr1,
                                             const float* __restrict__ Wr2,
                                             const float* __restrict__ Wcg,
                                             float* __restrict__ agg) {
    __shared__ float lWcgT[4096];   // [s][a][t] transposed for conflict-free C contraction
    __shared__ float lWr1[NB*NH];
    __shared__ float lWr2[NH*K];
    __shared__ float lup[512];
    __shared__ float lC[256];
    __shared__ float lY[16];
    __shared__ float lef[8];
    __shared__ float lh[NH];
    __shared__ float lRw[K];
    __shared__ int   lsnd;

    int n = blockIdx.x, tid = threadIdx.x;
    for (int j = tid; j < 4096; j += 256) {
        int a = j >> 8, s = (j >> 4) & 15, t = j & 15;
        lWcgT[s*256 + a*16 + t] = Wcg[j];
    }
    for (int j = tid; j < NB*NH; j += 256) lWr1[j] = Wr1[j];
    for (int j = tid; j < NH*K;  j += 256) lWr2[j] = Wr2[j];

    int k0 = tid >> 4, t0 = tid & 15;
    int start = row_ptr[n], end = row_ptr[n+1];
    float acc0 = 0.0f, acc1 = 0.0f;
    __syncthreads();

    for (int ii = start; ii < end; ++ii) {
        int e = perm[ii];
        if (tid < 16)       lY[tid] = Y[(size_t)e*16 + tid];
        else if (tid < 24)  lef[tid-16] = ef[(size_t)e*8 + (tid-16)];
        else if (tid == 24) lsnd = ei[e];
        __syncthreads();
        int snd = lsnd;
        lup[tid]       = up[(size_t)snd*512 + tid];
        lup[tid + 256] = up[(size_t)snd*512 + 256 + tid];
        // C[a,t] = sum_s Y[s] * Wcg[a,s,t]   (lWcgT read conflict-free: consecutive per lane)
        {
            float a = 0.0f;
#pragma unroll
            for (int s = 0; s < 16; s++) a += lY[s] * lWcgT[s*256 + tid];
            lC[tid] = a;
        }
        if (tid < NH) {
            float a = 0.0f;
#pragma unroll
            for (int b = 0; b < NB; b++) a += lef[b] * lWr1[b*NH + tid];
            lh[tid] = a / (1.0f + expf(-a));   // silu
        }
        __syncthreads();
        if (tid < K) {
            float a = 0.0f;
#pragma unroll
            for (int j = 0; j < NH; j++) a += lh[j] * lWr2[j*K + tid];
            lRw[tid] = a;
        }
        __syncthreads();
        {
            float d0 = 0.0f, d1 = 0.0f;
#pragma unroll
            for (int a = 0; a < 16; a++) {
                float c = lC[a*16 + t0];
                d0 += lup[k0*16 + a] * c;
                d1 += lup[(k0+16)*16 + a] * c;
            }
            acc0 += lRw[k0]      * d0;
            acc1 += lRw[k0 + 16] * d1;
        }
        __syncthreads();
    }
    agg[(size_t)n*512 + tid]       = acc0 * 0.0625f;   // / AVG_NEIGH
    agg[(size_t)n*512 + 256 + tid] = acc1 * 0.0625f;
}

// ---------------- per-layer node update: mid, quad, skip, prod; write feats and invariant slice ----------------
__global__ __launch_bounds__(256) void k_node(const float* __restrict__ agg,
                                              float* __restrict__ feats,
                                              const int* __restrict__ spec,
                                              const float* __restrict__ Wlin,
                                              const float* __restrict__ Wskip,
                                              const float* __restrict__ Wprod,
                                              const float* __restrict__ Wcg2,
                                              float* __restrict__ out,
                                              int layer) {
    __shared__ float lagg[512];
    __shared__ float lmid[512];
    __shared__ float lquad[512];
    __shared__ float lfeats[512];
    __shared__ float lWlin[1024];
    __shared__ float lWprod[1024];
    __shared__ float lWskip[1024];
    __shared__ float lWcg2[4096];

    int n = blockIdx.x, tid = threadIdx.x;
    int sp = spec[n];
    for (int j = tid; j < 512; j += 256) {
        lagg[j]   = agg[(size_t)n*512 + j];
        lfeats[j] = feats[(size_t)n*512 + j];
    }
    for (int j = tid; j < 1024; j += 256) {
        lWlin[j]  = Wlin[j];
        lWprod[j] = Wprod[j];
        lWskip[j] = Wskip[(size_t)sp*1024 + j];
    }
    for (int j = tid; j < 4096; j += 256) lWcg2[j] = Wcg2[j];
    __syncthreads();

    // mid[c,L] = sum_k agg[k,L] * Wlin[k,c]
#pragma unroll
    for (int jj = 0; jj < 2; jj++) {
        int idx = tid + jj*256;
        int c = idx >> 4, Lp = idx & 15;
        float a = 0.0f;
#pragma unroll
        for (int k = 0; k < K; k++) a += lagg[k*16 + Lp] * lWlin[k*K + c];
        lmid[idx] = a;
    }
    __syncthreads();

    // quad[k,t] = sum_{a,b} mid[k,a] mid[k,b] Wcg2[a,b,t];  sc[c,L] = sum_k feats[k,L] Wskip[k,c]
    float sc[2];
#pragma unroll
    for (int jj = 0; jj < 2; jj++) {
        int idx = tid + jj*256;
        int kk = idx >> 4, tt = idx & 15;
        float q = 0.0f;
#pragma unroll
        for (int a = 0; a < 16; a++) {
            float ma = lmid[kk*16 + a];
            float d = 0.0f;
#pragma unroll
            for (int b = 0; b < 16; b++) d += lmid[kk*16 + b] * lWcg2[a*256 + b*16 + tt];
            q += ma * d;
        }
        lquad[idx] = q;
        float s = 0.0f;
#pragma unroll
        for (int k = 0; k < K; k++) s += lfeats[k*16 + tt] * lWskip[k*K + kk];
        sc[jj] = s;
    }
    __syncthreads();

    // feats_new[c,L] = sum_k (mid[k,L]+quad[k,L]) * Wprod[k,c] + sc[c,L]
#pragma unroll
    for (int jj = 0; jj < 2; jj++) {
        int idx = tid + jj*256;
        int c = idx >> 4, Lp = idx & 15;
        float a = 0.0f;
#pragma unroll
        for (int k = 0; k < K; k++) a += (lmid[k*16 + Lp] + lquad[k*16 + Lp]) * lWprod[k*K + c];
        a += sc[jj];
        feats[(size_t)n*512 + idx] = a;
        if (Lp == 0) out[(size_t)n*(NL*K) + layer*K + c] = a;
    }
}

extern "C" void kernel_launch(void* const* d_in, const int* in_sizes, int n_in,
                              void* d_out, int out_size, void* d_ws, size_t ws_size,
                              hipStream_t stream) {
    const float* pos     = (const float*)d_in[0];
    const float* shifts  = (const float*)d_in[1];
    const float* attrs   = (const float*)d_in[2];
    const float* W_embed = (const float*)d_in[3];
    const float* W_up    = (const float*)d_in[4];
    const float* W_r1    = (const float*)d_in[5];
    const float* W_r2    = (const float*)d_in[6];
    const float* W_lin   = (const float*)d_in[7];
    const float* W_skip  = (const float*)d_in[8];
    const float* W_prod  = (const float*)d_in[9];
    const float* Wcg     = (const float*)d_in[10];
    const float* Wcg2    = (const float*)d_in[11];
    const int*   ei      = (const int*)d_in[12];
    float* out = (float*)d_out;

    uint8_t* p = (uint8_t*)d_ws;
    auto alloc = [&](size_t bytes) -> void* {
        void* r = (void*)p;
        p += (bytes + 255) & ~size_t(255);
        return r;
    };
    float* Y      = (float*)alloc((size_t)N_EDGES * 16 * sizeof(float));
    float* ef     = (float*)alloc((size_t)N_EDGES * 8  * sizeof(float));
    float* feats  = (float*)alloc((size_t)N_NODES * K * LDIM * sizeof(float));
    float* up     = (float*)alloc((size_t)N_NODES * K * LDIM * sizeof(float));
    float* agg    = (float*)alloc((size_t)N_NODES * K * LDIM * sizeof(float));
    int* counts   = (int*)alloc((size_t)N_NODES * sizeof(int));
    int* woff     = (int*)alloc((size_t)N_NODES * sizeof(int));
    int* row_ptr  = (int*)alloc((size_t)(N_NODES + 1) * sizeof(int));
    int* perm     = (int*)alloc((size_t)N_EDGES * sizeof(int));
    int* spec     = (int*)alloc((size_t)N_NODES * sizeof(int));

    hipMemsetAsync(counts, 0, N_NODES * sizeof(int), stream);
    k_geom<<<(N_EDGES + 255) / 256, 256, 0, stream>>>(pos, shifts, ei, Y, ef, counts);
    k_scan<<<1, 1024, 0, stream>>>(counts, row_ptr, woff);
    k_scatter<<<(N_EDGES + 255) / 256, 256, 0, stream>>>(ei, woff, perm);
    k_embed<<<(N_NODES * K + 255) / 256, 256, 0, stream>>>(attrs, W_embed, feats, spec);

    for (int i = 0; i < NL; i++) {
        k_up<<<N_NODES, 256, 0, stream>>>(feats, W_up + (size_t)i*K*K, up);
        k_agg<<<N_NODES, 256, 0, stream>>>(up, Y, ef, ei, row_ptr, perm,
                                           W_r1 + (size_t)i*NB*NH, W_r2 + (size_t)i*NH*K, Wcg, agg);
        k_node<<<N_NODES, 256, 0, stream>>>(agg, feats, spec,
                                            W_lin + (size_t)i*K*K, W_skip + (size_t)i*NZ*K*K,
                                            W_prod + (size_t)i*K*K, Wcg2, out, i);
    }
}

// Round 2
// 464.394 us; speedup vs baseline: 2.5462x; 2.5462x over previous
//
#include <hip/hip_runtime.h>
#include <math.h>
#include <stdint.h>

#define N_NODES 8000
#define N_EDGES 128000
#define NZ 10
#define K 32
#define LDIM 16
#define NB 8
#define NH 32
#define NL 2

// wave-level LDS producer->consumer sync (no cross-wave sharing): drain DS ops,
// pin scheduling (guide rule #18: sched_barrier after inline-asm waitcnt).
#define WAVE_SYNC() do { \
    asm volatile("s_waitcnt lgkmcnt(0)" ::: "memory"); \
    __builtin_amdgcn_wave_barrier(); \
    __builtin_amdgcn_sched_barrier(0); \
} while (0)

// ---------------- edge geometry: Y (sph harm l=0..3), radial basis, rcv histogram ----------------
__global__ __launch_bounds__(256) void k_geom(const float* __restrict__ pos,
                                              const float* __restrict__ shifts,
                                              const int* __restrict__ ei,
                                              float* __restrict__ Y,
                                              float* __restrict__ ef,
                                              int* __restrict__ counts) {
    int e = blockIdx.x * blockDim.x + threadIdx.x;
    if (e >= N_EDGES) return;
    int snd = ei[e];
    int rcv = ei[N_EDGES + e];
    float vx = pos[rcv*3+0] - pos[snd*3+0] + shifts[e*3+0];
    float vy = pos[rcv*3+1] - pos[snd*3+1] + shifts[e*3+1];
    float vz = pos[rcv*3+2] - pos[snd*3+2] + shifts[e*3+2];
    float r2 = vx*vx + vy*vy + vz*vz;
    float r  = sqrtf(fmaxf(r2, 1e-12f));
    float inv = 1.0f / r;
    float x = vx*inv, y = vy*inv, z = vz*inv;

    const float s3    = 1.7320508075688772f;
    const float s5    = 2.2360679774997896f;
    const float s15   = 3.8729833462074170f;
    const float s35_8 = 2.0916500663351885f;
    const float s105  = 10.246950765959598f;
    const float s21_8 = 1.6201851746019651f;
    const float s7    = 2.6457513110645907f;

    float Yv[16];
    Yv[0]  = 1.0f;
    Yv[1]  = s3*x;  Yv[2] = s3*y;  Yv[3] = s3*z;
    Yv[4]  = s15*x*y;
    Yv[5]  = s15*y*z;
    Yv[6]  = 0.5f*s5*(3.0f*z*z - 1.0f);
    Yv[7]  = s15*x*z;
    Yv[8]  = 0.5f*s15*(x*x - y*y);
    Yv[9]  = s35_8*y*(3.0f*x*x - y*y);
    Yv[10] = s105*x*y*z;
    Yv[11] = s21_8*y*(5.0f*z*z - 1.0f);
    Yv[12] = 0.5f*s7*(5.0f*z*z*z - 3.0f*z);
    Yv[13] = s21_8*x*(5.0f*z*z - 1.0f);
    Yv[14] = 0.5f*s105*z*(x*x - y*y);
    Yv[15] = s35_8*x*(x*x - 3.0f*y*y);
#pragma unroll
    for (int j = 0; j < 16; j++) Y[(size_t)e*16 + j] = Yv[j];

    float uu = fminf(fmaxf(r * 0.2f, 0.0f), 1.0f);
    float u2 = uu*uu;
    float u6 = u2*u2*u2;
    float f  = 1.0f - 28.0f*u6 + 48.0f*u6*uu - 21.0f*u6*u2;
    float c  = 0.632455532033676f * inv * f;
    const float PI5 = 3.14159265358979323846f * 0.2f;
#pragma unroll
    for (int n = 1; n <= 8; n++) ef[(size_t)e*8 + n - 1] = c * sinf((float)n * PI5 * r);

    atomicAdd(&counts[rcv], 1);
}

// ---------------- exclusive scan of counts -> row_ptr ----------------
__global__ __launch_bounds__(1024) void k_scan(const int* __restrict__ counts,
                                               int* __restrict__ row_ptr,
                                               int* __restrict__ woff) {
    __shared__ int s[8192];
    int tid = threadIdx.x;
    for (int j = tid; j < 8192; j += 1024) s[j] = (j < N_NODES) ? counts[j] : 0;
    __syncthreads();
    for (int off = 1; off < 8192; off <<= 1) {
        int v[8];
#pragma unroll
        for (int jj = 0; jj < 8; jj++) {
            int idx = tid + jj*1024;
            v[jj] = s[idx] + ((idx >= off) ? s[idx - off] : 0);
        }
        __syncthreads();
#pragma unroll
        for (int jj = 0; jj < 8; jj++) s[tid + jj*1024] = v[jj];
        __syncthreads();
    }
    for (int j = tid; j <= N_NODES; j += 1024) {
        int v = (j == 0) ? 0 : s[j-1];
        row_ptr[j] = v;
        if (j < N_NODES) woff[j] = v;
    }
}

// ---------------- scatter edge ids into CSR order ----------------
__global__ __launch_bounds__(256) void k_scatter(const int* __restrict__ ei,
                                                 int* __restrict__ woff,
                                                 int* __restrict__ perm) {
    int e = blockIdx.x * blockDim.x + threadIdx.x;
    if (e >= N_EDGES) return;
    int r = ei[N_EDGES + e];
    int pp = atomicAdd(&woff[r], 1);
    perm[pp] = e;
}

// ---------------- node embedding ----------------
__global__ __launch_bounds__(256) void k_embed(const float* __restrict__ attrs,
                                               const float* __restrict__ We,
                                               float* __restrict__ feats,
                                               int* __restrict__ spec) {
    int i = blockIdx.x * blockDim.x + threadIdx.x;
    if (i >= N_NODES * K) return;
    int n = i >> 5, k = i & 31;
    float a = 0.0f;
#pragma unroll
    for (int z = 0; z < NZ; z++) a += attrs[n*NZ + z] * We[z*K + k];
    float* f = feats + (size_t)n*(K*LDIM) + k*LDIM;
    f[0] = a;
#pragma unroll
    for (int j = 1; j < LDIM; j++) f[j] = 0.0f;
    if (k == 0) {
        int sp = 0; float best = -1.0f;
        for (int z = 0; z < NZ; z++) { float v = attrs[n*NZ + z]; if (v > best) { best = v; sp = z; } }
        spec[n] = sp;
    }
}

// ---------------- per-layer: up = feats @ W_up ----------------
__global__ __launch_bounds__(256) void k_up(const float* __restrict__ feats,
                                            const float* __restrict__ Wup,
                                            float* __restrict__ up) {
    __shared__ float lf[512];
    __shared__ float lw[1024];
    int n = blockIdx.x, tid = threadIdx.x;
    const float* f = feats + (size_t)n*512;
    for (int j = tid; j < 512;  j += 256) lf[j] = f[j];
    for (int j = tid; j < 1024; j += 256) lw[j] = Wup[j];
    __syncthreads();
#pragma unroll
    for (int jj = 0; jj < 2; jj++) {
        int idx = tid + jj*256;
        int c = idx >> 4, Lp = idx & 15;
        float a = 0.0f;
#pragma unroll
        for (int k = 0; k < K; k++) a += lf[k*16 + Lp] * lw[k*K + c];
        up[(size_t)n*512 + idx] = a;
    }
}

// ---------------- per-layer radial MLP per edge: Rw[e,k] = silu(ef@W1)@W2 ----------------
__global__ __launch_bounds__(256) void k_radial(const float* __restrict__ ef,
                                                const float* __restrict__ W1,
                                                const float* __restrict__ W2,
                                                float* __restrict__ Rw) {
    __shared__ float lW1[NB*NH];
    __shared__ float lW2[NH*K];
    int tid = threadIdx.x;
    for (int j = tid; j < NB*NH; j += 256) lW1[j] = W1[j];
    for (int j = tid; j < NH*K;  j += 256) lW2[j] = W2[j];
    __syncthreads();
    int e = blockIdx.x * 256 + tid;
    if (e >= N_EDGES) return;
    const float4* e4 = (const float4*)(ef + (size_t)e*8);
    float4 ea = e4[0], eb = e4[1];
    float efr[8] = {ea.x, ea.y, ea.z, ea.w, eb.x, eb.y, eb.z, eb.w};
    float rw[32];
#pragma unroll
    for (int k = 0; k < 32; ++k) rw[k] = 0.0f;
    for (int j = 0; j < NH; ++j) {
        float h = 0.0f;
#pragma unroll
        for (int b = 0; b < NB; ++b) h += efr[b] * lW1[b*NH + j];
        float s = h / (1.0f + expf(-h));
        const float4* w2r = (const float4*)(lW2 + j*K);
#pragma unroll
        for (int kq = 0; kq < 8; ++kq) {
            float4 w = w2r[kq];
            rw[kq*4+0] += s*w.x; rw[kq*4+1] += s*w.y;
            rw[kq*4+2] += s*w.z; rw[kq*4+3] += s*w.w;
        }
    }
    float4* o = (float4*)(Rw + (size_t)e*32);
#pragma unroll
    for (int kq = 0; kq < 8; ++kq)
        o[kq] = make_float4(rw[kq*4], rw[kq*4+1], rw[kq*4+2], rw[kq*4+3]);
}

// ---------------- aggregation: one wave per receiving node, no barriers in edge loop ----------------
__global__ __launch_bounds__(256, 4) void k_agg(const float* __restrict__ up,
                                                const float* __restrict__ Y,
                                                const float* __restrict__ Rw,
                                                const int* __restrict__ ei,
                                                const int* __restrict__ row_ptr,
                                                const int* __restrict__ perm,
                                                const float* __restrict__ Wcg,
                                                float* __restrict__ agg) {
    __shared__ float lWs[4096];      // s-major: lWs[s*256 + a*16 + t] = Wcg[a,s,t]
    __shared__ float lC[4*256];      // per-wave C[a][t]
    __shared__ float lup[4*544];     // per-wave up[snd], rows padded to 17

    int tid = threadIdx.x;
    for (int j = tid; j < 4096; j += 256) {
        int a = j >> 8, s = (j >> 4) & 15, t = j & 15;
        lWs[s*256 + a*16 + t] = Wcg[j];
    }
    __syncthreads();

    int wave = tid >> 6;
    int lane = tid & 63;
    int n = blockIdx.x * 4 + wave;
    int k0 = lane & 15;              // channel (and +16)
    int tq = lane >> 4;              // t-quad 0..3
    float* lCw  = lC  + wave*256;
    float* lupw = lup + wave*544;

    int start = row_ptr[n], end = row_ptr[n+1];
    float acc0[4] = {0,0,0,0}, acc1[4] = {0,0,0,0};

    int e_cur = 0, snd_cur = 0;
    if (start < end) { e_cur = perm[start]; snd_cur = ei[e_cur]; }

    for (int ii = start; ii < end; ++ii) {
        int e = e_cur, snd = snd_cur;
        if (ii + 1 < end) { e_cur = perm[ii+1]; snd_cur = ei[e_cur]; }  // prefetch

        // ---- Y row into regs (wave-uniform broadcast) ----
        const float4* Y4 = (const float4*)(Y + (size_t)e*16);
        float4 ya = Y4[0], yb = Y4[1], yc = Y4[2], yd = Y4[3];
        float yv[16] = {ya.x,ya.y,ya.z,ya.w, yb.x,yb.y,yb.z,yb.w,
                        yc.x,yc.y,yc.z,yc.w, yd.x,yd.y,yd.z,yd.w};

        // ---- radial weights for this edge ----
        float rw0 = Rw[(size_t)e*32 + k0];
        float rw1 = Rw[(size_t)e*32 + k0 + 16];

        // ---- C[a][t] = sum_s Y[s]*Wcg[a,s,t]; lane owns flat [lane*4 .. +3] ----
        float4 c = {0,0,0,0};
#pragma unroll
        for (int s = 0; s < 16; ++s) {
            float4 w = *((const float4*)(lWs + s*256 + lane*4));   // fully-sequential b128
            c.x += yv[s]*w.x; c.y += yv[s]*w.y; c.z += yv[s]*w.z; c.w += yv[s]*w.w;
        }
        *((float4*)(lCw + lane*4)) = c;

        // ---- cooperative coalesced stage of up[snd] (2KB) into padded LDS ----
        {
            int gk = lane >> 2;
            int d0 = (lane & 3) * 4;
            float4 u0 = *(const float4*)(up + (size_t)snd*512 + gk*16 + d0);
            float4 u1 = *(const float4*)(up + (size_t)snd*512 + (gk+16)*16 + d0);
            float* w0 = lupw + gk*17 + d0;
            w0[0]=u0.x; w0[1]=u0.y; w0[2]=u0.z; w0[3]=u0.w;
            float* w1 = lupw + (gk+16)*17 + d0;
            w1[0]=u1.x; w1[1]=u1.y; w1[2]=u1.z; w1[3]=u1.w;
        }
        WAVE_SYNC();

        // ---- msg: d[k,t] = sum_a up[k,a]*C[a,t]; acc += Rw[k]*d ----
        float d0a[4] = {0,0,0,0}, d1a[4] = {0,0,0,0};
#pragma unroll
        for (int a = 0; a < 16; ++a) {
            float4 cv = *((const float4*)(lCw + a*16 + tq*4));   // 4 distinct addrs, bcast
            float ua = lupw[k0*17 + a];                          // conflict-free (pad 17)
            float ub = lupw[(k0+16)*17 + a];
            d0a[0] += ua*cv.x; d0a[1] += ua*cv.y; d0a[2] += ua*cv.z; d0a[3] += ua*cv.w;
            d1a[0] += ub*cv.x; d1a[1] += ub*cv.y; d1a[2] += ub*cv.z; d1a[3] += ub*cv.w;
        }
#pragma unroll
        for (int j = 0; j < 4; ++j) { acc0[j] += rw0*d0a[j]; acc1[j] += rw1*d1a[j]; }
        WAVE_SYNC();   // protect lC/lup against next iteration's overwrites
    }

    float* o0 = agg + (size_t)n*512 + k0*16 + tq*4;
    float* o1 = agg + (size_t)n*512 + (k0+16)*16 + tq*4;
    *(float4*)o0 = make_float4(acc0[0]*0.0625f, acc0[1]*0.0625f, acc0[2]*0.0625f, acc0[3]*0.0625f);
    *(float4*)o1 = make_float4(acc1[0]*0.0625f, acc1[1]*0.0625f, acc1[2]*0.0625f, acc1[3]*0.0625f);
}

// ---------------- node update: channel-per-lane; 8 nodes/block ----------------
__global__ __launch_bounds__(256, 2) void k_node(const float* __restrict__ agg,
                                                 float* __restrict__ feats,
                                                 const int* __restrict__ spec,
                                                 const float* __restrict__ Wlin,
                                                 const float* __restrict__ Wskip,
                                                 const float* __restrict__ Wprod,
                                                 const float* __restrict__ Wcg2,
                                                 float* __restrict__ out,
                                                 int layer) {
    __shared__ float lWcg2[4096];
    __shared__ float lWlin[1024];
    __shared__ float lWprod[1024];
    __shared__ float lagg[4096];     // 8 nodes x 512, reused as s = mid+quad
    __shared__ float lmid[4352];     // 8 nodes x (32 rows padded to 17)

    int tid = threadIdx.x;
    int nbase = blockIdx.x * 8;
    for (int j = tid; j < 4096; j += 256) lWcg2[j] = Wcg2[j];
    for (int j = tid; j < 1024; j += 256) { lWlin[j] = Wlin[j]; lWprod[j] = Wprod[j]; }
    {
        const float4* src = (const float4*)(agg + (size_t)nbase*512);
        float4* dst = (float4*)lagg;
        for (int j = tid; j < 1024; j += 256) dst[j] = src[j];
    }
    __syncthreads();

    int lane = tid & 63;
    int wave = tid >> 6;
    int c = lane & 31;
    int node = wave*2 + (lane >> 5);
    int n = nbase + node;
    const float* la = lagg + node*512;

    // ---- mid[c][t] = sum_k agg[k][t] * Wlin[k][c] ----
    float m[16];
#pragma unroll
    for (int t = 0; t < 16; ++t) m[t] = 0.0f;
    for (int k = 0; k < 32; ++k) {
        float w = lWlin[k*32 + c];
        const float4* ar = (const float4*)(la + k*16);   // broadcast
        float4 a0 = ar[0], a1 = ar[1], a2 = ar[2], a3 = ar[3];
        m[0]+=a0.x*w;  m[1]+=a0.y*w;  m[2]+=a0.z*w;  m[3]+=a0.w*w;
        m[4]+=a1.x*w;  m[5]+=a1.y*w;  m[6]+=a1.z*w;  m[7]+=a1.w*w;
        m[8]+=a2.x*w;  m[9]+=a2.y*w;  m[10]+=a2.z*w; m[11]+=a2.w*w;
        m[12]+=a3.x*w; m[13]+=a3.y*w; m[14]+=a3.z*w; m[15]+=a3.w*w;
    }

    // mirror m to padded LDS for runtime-a access (conflict-free: stride 17)
    float* lmidw = lmid + node*544 + c*17;
#pragma unroll
    for (int a = 0; a < 16; ++a) lmidw[a] = m[a];
    WAVE_SYNC();

    // ---- quad[c][t] = sum_{a,b} m[a]*m[b]*Wcg2[a,b,t] ----
    float q[16];
#pragma unroll
    for (int t = 0; t < 16; ++t) q[t] = 0.0f;
    for (int a = 0; a < 16; ++a) {
        float ma = lmidw[a];                 // own row, runtime index via LDS
        const float* wbase = lWcg2 + a*256;
#pragma unroll
        for (int b = 0; b < 16; ++b) {
            float p = ma * m[b];
            const float4* w4 = (const float4*)(wbase + b*16);  // wave-uniform broadcast
            float4 w0 = w4[0], w1 = w4[1], w2 = w4[2], w3 = w4[3];
            q[0]+=p*w0.x;  q[1]+=p*w0.y;  q[2]+=p*w0.z;  q[3]+=p*w0.w;
            q[4]+=p*w1.x;  q[5]+=p*w1.y;  q[6]+=p*w1.z;  q[7]+=p*w1.w;
            q[8]+=p*w2.x;  q[9]+=p*w2.y;  q[10]+=p*w2.z; q[11]+=p*w2.w;
            q[12]+=p*w3.x; q[13]+=p*w3.y; q[14]+=p*w3.z; q[15]+=p*w3.w;
        }
    }

    // ---- s = mid + quad into lagg (reuse; agg fully consumed) ----
    float* lsrow = lagg + node*512 + c*16;
#pragma unroll
    for (int tq = 0; tq < 4; ++tq)
        *((float4*)(lsrow + tq*4)) = make_float4(m[tq*4]+q[tq*4], m[tq*4+1]+q[tq*4+1],
                                                 m[tq*4+2]+q[tq*4+2], m[tq*4+3]+q[tq*4+3]);
    WAVE_SYNC();

    // ---- out[c][t] = sum_k s[k][t]*Wprod[k][c] + sum_k feats[k][t]*Wskip[sp][k][c] ----
    int sp = spec[n];
    const float* wsk = Wskip + (size_t)sp*1024;
    const float* ls_node = lagg + node*512;
    const float* fg = feats + (size_t)n*512;
    float acc[16];
#pragma unroll
    for (int t = 0; t < 16; ++t) acc[t] = 0.0f;
    for (int k = 0; k < 32; ++k) {
        float wp = lWprod[k*32 + c];
        float wv = wsk[k*32 + c];                        // global, coalesced, L1-hot
        const float4* sr = (const float4*)(ls_node + k*16);
        float4 s0 = sr[0], s1 = sr[1], s2 = sr[2], s3 = sr[3];
        const float4* fr = (const float4*)(fg + k*16);   // global broadcast
        float4 f0 = fr[0], f1 = fr[1], f2 = fr[2], f3 = fr[3];
        acc[0]+=s0.x*wp+f0.x*wv;  acc[1]+=s0.y*wp+f0.y*wv;
        acc[2]+=s0.z*wp+f0.z*wv;  acc[3]+=s0.w*wp+f0.w*wv;
        acc[4]+=s1.x*wp+f1.x*wv;  acc[5]+=s1.y*wp+f1.y*wv;
        acc[6]+=s1.z*wp+f1.z*wv;  acc[7]+=s1.w*wp+f1.w*wv;
        acc[8]+=s2.x*wp+f2.x*wv;  acc[9]+=s2.y*wp+f2.y*wv;
        acc[10]+=s2.z*wp+f2.z*wv; acc[11]+=s2.w*wp+f2.w*wv;
        acc[12]+=s3.x*wp+f3.x*wv; acc[13]+=s3.y*wp+f3.y*wv;
        acc[14]+=s3.z*wp+f3.z*wv; acc[15]+=s3.w*wp+f3.w*wv;
    }
    float* fo = feats + (size_t)n*512 + c*16;
#pragma unroll
    for (int tq = 0; tq < 4; ++tq)
        *((float4*)(fo + tq*4)) = make_float4(acc[tq*4], acc[tq*4+1], acc[tq*4+2], acc[tq*4+3]);
    out[(size_t)n*(NL*K) + layer*K + c] = acc[0];
}

extern "C" void kernel_launch(void* const* d_in, const int* in_sizes, int n_in,
                              void* d_out, int out_size, void* d_ws, size_t ws_size,
                              hipStream_t stream) {
    const float* pos     = (const float*)d_in[0];
    const float* shifts  = (const float*)d_in[1];
    const float* attrs   = (const float*)d_in[2];
    const float* W_embed = (const float*)d_in[3];
    const float* W_up    = (const float*)d_in[4];
    const float* W_r1    = (const float*)d_in[5];
    const float* W_r2    = (const float*)d_in[6];
    const float* W_lin   = (const float*)d_in[7];
    const float* W_skip  = (const float*)d_in[8];
    const float* W_prod  = (const float*)d_in[9];
    const float* Wcg     = (const float*)d_in[10];
    const float* Wcg2    = (const float*)d_in[11];
    const int*   ei      = (const int*)d_in[12];
    float* out = (float*)d_out;

    uint8_t* p = (uint8_t*)d_ws;
    auto alloc = [&](size_t bytes) -> void* {
        void* r = (void*)p;
        p += (bytes + 255) & ~size_t(255);
        return r;
    };
    float* Y      = (float*)alloc((size_t)N_EDGES * 16 * sizeof(float));
    float* ef     = (float*)alloc((size_t)N_EDGES * 8  * sizeof(float));
    float* Rw     = (float*)alloc((size_t)N_EDGES * K  * sizeof(float));
    float* feats  = (float*)alloc((size_t)N_NODES * K * LDIM * sizeof(float));
    float* up     = (float*)alloc((size_t)N_NODES * K * LDIM * sizeof(float));
    float* agg    = (float*)alloc((size_t)N_NODES * K * LDIM * sizeof(float));
    int* counts   = (int*)alloc((size_t)N_NODES * sizeof(int));
    int* woff     = (int*)alloc((size_t)N_NODES * sizeof(int));
    int* row_ptr  = (int*)alloc((size_t)(N_NODES + 1) * sizeof(int));
    int* perm     = (int*)alloc((size_t)N_EDGES * sizeof(int));
    int* spec     = (int*)alloc((size_t)N_NODES * sizeof(int));

    hipMemsetAsync(counts, 0, N_NODES * sizeof(int), stream);
    k_geom<<<(N_EDGES + 255) / 256, 256, 0, stream>>>(pos, shifts, ei, Y, ef, counts);
    k_scan<<<1, 1024, 0, stream>>>(counts, row_ptr, woff);
    k_scatter<<<(N_EDGES + 255) / 256, 256, 0, stream>>>(ei, woff, perm);
    k_embed<<<(N_NODES * K + 255) / 256, 256, 0, stream>>>(attrs, W_embed, feats, spec);

    for (int i = 0; i < NL; i++) {
        k_up<<<N_NODES, 256, 0, stream>>>(feats, W_up + (size_t)i*K*K, up);
        k_radial<<<N_EDGES/256, 256, 0, stream>>>(ef, W_r1 + (size_t)i*NB*NH, W_r2 + (size_t)i*NH*K, Rw);
        k_agg<<<N_NODES/4, 256, 0, stream>>>(up, Y, Rw, ei, row_ptr, perm, Wcg, agg);
        k_node<<<N_NODES/8, 256, 0, stream>>>(agg, feats, spec,
                                              W_lin + (size_t)i*K*K, W_skip + (size_t)i*NZ*K*K,
                                              W_prod + (size_t)i*K*K, Wcg2, out, i);
    }
}

// Round 3
// 452.778 us; speedup vs baseline: 2.6116x; 1.0257x over previous
//
#include <hip/hip_runtime.h>
#include <math.h>
#include <stdint.h>

#define N_NODES 8000
#define N_EDGES 128000
#define NZ 10
#define K 32
#define LDIM 16
#define NB 8
#define NH 32
#define NL 2

// wave-level LDS producer->consumer sync (no cross-wave sharing): drain DS ops,
// pin scheduling (guide rule #18: sched_barrier after inline-asm waitcnt).
#define WAVE_SYNC() do { \
    asm volatile("s_waitcnt lgkmcnt(0)" ::: "memory"); \
    __builtin_amdgcn_wave_barrier(); \
    __builtin_amdgcn_sched_barrier(0); \
} while (0)

__device__ inline float4 shfl_xor4(float4 v, int mask) {
    return make_float4(__shfl_xor(v.x, mask, 64), __shfl_xor(v.y, mask, 64),
                       __shfl_xor(v.z, mask, 64), __shfl_xor(v.w, mask, 64));
}

// ---------------- edge geometry: Y (sph harm l=0..3), radial basis, rcv histogram ----------------
__global__ __launch_bounds__(256) void k_geom(const float* __restrict__ pos,
                                              const float* __restrict__ shifts,
                                              const int* __restrict__ ei,
                                              float* __restrict__ Y,
                                              float* __restrict__ ef,
                                              int* __restrict__ counts) {
    int e = blockIdx.x * blockDim.x + threadIdx.x;
    if (e >= N_EDGES) return;
    int snd = ei[e];
    int rcv = ei[N_EDGES + e];
    float vx = pos[rcv*3+0] - pos[snd*3+0] + shifts[e*3+0];
    float vy = pos[rcv*3+1] - pos[snd*3+1] + shifts[e*3+1];
    float vz = pos[rcv*3+2] - pos[snd*3+2] + shifts[e*3+2];
    float r2 = vx*vx + vy*vy + vz*vz;
    float r  = sqrtf(fmaxf(r2, 1e-12f));
    float inv = 1.0f / r;
    float x = vx*inv, y = vy*inv, z = vz*inv;

    const float s3    = 1.7320508075688772f;
    const float s5    = 2.2360679774997896f;
    const float s15   = 3.8729833462074170f;
    const float s35_8 = 2.0916500663351885f;
    const float s105  = 10.246950765959598f;
    const float s21_8 = 1.6201851746019651f;
    const float s7    = 2.6457513110645907f;

    float Yv[16];
    Yv[0]  = 1.0f;
    Yv[1]  = s3*x;  Yv[2] = s3*y;  Yv[3] = s3*z;
    Yv[4]  = s15*x*y;
    Yv[5]  = s15*y*z;
    Yv[6]  = 0.5f*s5*(3.0f*z*z - 1.0f);
    Yv[7]  = s15*x*z;
    Yv[8]  = 0.5f*s15*(x*x - y*y);
    Yv[9]  = s35_8*y*(3.0f*x*x - y*y);
    Yv[10] = s105*x*y*z;
    Yv[11] = s21_8*y*(5.0f*z*z - 1.0f);
    Yv[12] = 0.5f*s7*(5.0f*z*z*z - 3.0f*z);
    Yv[13] = s21_8*x*(5.0f*z*z - 1.0f);
    Yv[14] = 0.5f*s105*z*(x*x - y*y);
    Yv[15] = s35_8*x*(x*x - 3.0f*y*y);
#pragma unroll
    for (int j = 0; j < 16; j++) Y[(size_t)e*16 + j] = Yv[j];

    float uu = fminf(fmaxf(r * 0.2f, 0.0f), 1.0f);
    float u2 = uu*uu;
    float u6 = u2*u2*u2;
    float f  = 1.0f - 28.0f*u6 + 48.0f*u6*uu - 21.0f*u6*u2;
    float c  = 0.632455532033676f * inv * f;
    const float PI5 = 3.14159265358979323846f * 0.2f;
#pragma unroll
    for (int n = 1; n <= 8; n++) ef[(size_t)e*8 + n - 1] = c * sinf((float)n * PI5 * r);

    atomicAdd(&counts[rcv], 1);
}

// ---------------- exclusive scan of counts -> row_ptr ----------------
__global__ __launch_bounds__(1024) void k_scan(const int* __restrict__ counts,
                                               int* __restrict__ row_ptr,
                                               int* __restrict__ woff) {
    __shared__ int s[8192];
    int tid = threadIdx.x;
    for (int j = tid; j < 8192; j += 1024) s[j] = (j < N_NODES) ? counts[j] : 0;
    __syncthreads();
    for (int off = 1; off < 8192; off <<= 1) {
        int v[8];
#pragma unroll
        for (int jj = 0; jj < 8; jj++) {
            int idx = tid + jj*1024;
            v[jj] = s[idx] + ((idx >= off) ? s[idx - off] : 0);
        }
        __syncthreads();
#pragma unroll
        for (int jj = 0; jj < 8; jj++) s[tid + jj*1024] = v[jj];
        __syncthreads();
    }
    for (int j = tid; j <= N_NODES; j += 1024) {
        int v = (j == 0) ? 0 : s[j-1];
        row_ptr[j] = v;
        if (j < N_NODES) woff[j] = v;
    }
}

// ---------------- scatter edge ids into CSR order ----------------
__global__ __launch_bounds__(256) void k_scatter(const int* __restrict__ ei,
                                                 int* __restrict__ woff,
                                                 int* __restrict__ perm) {
    int e = blockIdx.x * blockDim.x + threadIdx.x;
    if (e >= N_EDGES) return;
    int r = ei[N_EDGES + e];
    int pp = atomicAdd(&woff[r], 1);
    perm[pp] = e;
}

// ---------------- node embedding ----------------
__global__ __launch_bounds__(256) void k_embed(const float* __restrict__ attrs,
                                               const float* __restrict__ We,
                                               float* __restrict__ feats,
                                               int* __restrict__ spec) {
    int i = blockIdx.x * blockDim.x + threadIdx.x;
    if (i >= N_NODES * K) return;
    int n = i >> 5, k = i & 31;
    float a = 0.0f;
#pragma unroll
    for (int z = 0; z < NZ; z++) a += attrs[n*NZ + z] * We[z*K + k];
    float* f = feats + (size_t)n*(K*LDIM) + k*LDIM;
    f[0] = a;
#pragma unroll
    for (int j = 1; j < LDIM; j++) f[j] = 0.0f;
    if (k == 0) {
        int sp = 0; float best = -1.0f;
        for (int z = 0; z < NZ; z++) { float v = attrs[n*NZ + z]; if (v > best) { best = v; sp = z; } }
        spec[n] = sp;
    }
}

// ---------------- per-layer: up = feats @ W_up ----------------
__global__ __launch_bounds__(256) void k_up(const float* __restrict__ feats,
                                            const float* __restrict__ Wup,
                                            float* __restrict__ up) {
    __shared__ float lf[512];
    __shared__ float lw[1024];
    int n = blockIdx.x, tid = threadIdx.x;
    const float* f = feats + (size_t)n*512;
    for (int j = tid; j < 512;  j += 256) lf[j] = f[j];
    for (int j = tid; j < 1024; j += 256) lw[j] = Wup[j];
    __syncthreads();
#pragma unroll
    for (int jj = 0; jj < 2; jj++) {
        int idx = tid + jj*256;
        int c = idx >> 4, Lp = idx & 15;
        float a = 0.0f;
#pragma unroll
        for (int k = 0; k < K; k++) a += lf[k*16 + Lp] * lw[k*K + c];
        up[(size_t)n*512 + idx] = a;
    }
}

// ---------------- per-layer radial MLP per edge: Rw[e,k] = silu(ef@W1)@W2 ----------------
__global__ __launch_bounds__(256) void k_radial(const float* __restrict__ ef,
                                                const float* __restrict__ W1,
                                                const float* __restrict__ W2,
                                                float* __restrict__ Rw) {
    __shared__ float lW1[NB*NH];
    __shared__ float lW2[NH*K];
    int tid = threadIdx.x;
    for (int j = tid; j < NB*NH; j += 256) lW1[j] = W1[j];
    for (int j = tid; j < NH*K;  j += 256) lW2[j] = W2[j];
    __syncthreads();
    int e = blockIdx.x * 256 + tid;
    if (e >= N_EDGES) return;
    const float4* e4 = (const float4*)(ef + (size_t)e*8);
    float4 ea = e4[0], eb = e4[1];
    float efr[8] = {ea.x, ea.y, ea.z, ea.w, eb.x, eb.y, eb.z, eb.w};
    float rw[32];
#pragma unroll
    for (int k = 0; k < 32; ++k) rw[k] = 0.0f;
    for (int j = 0; j < NH; ++j) {
        float h = 0.0f;
#pragma unroll
        for (int b = 0; b < NB; ++b) h += efr[b] * lW1[b*NH + j];
        float s = h / (1.0f + expf(-h));
        const float4* w2r = (const float4*)(lW2 + j*K);
#pragma unroll
        for (int kq = 0; kq < 8; ++kq) {
            float4 w = w2r[kq];
            rw[kq*4+0] += s*w.x; rw[kq*4+1] += s*w.y;
            rw[kq*4+2] += s*w.z; rw[kq*4+3] += s*w.w;
        }
    }
    float4* o = (float4*)(Rw + (size_t)e*32);
#pragma unroll
    for (int kq = 0; kq < 8; ++kq)
        o[kq] = make_float4(rw[kq*4], rw[kq*4+1], rw[kq*4+2], rw[kq*4+3]);
}

// ---------------- aggregation: one wave per node; up via shfl, C double-buffered ----------------
__global__ __launch_bounds__(256, 4) void k_agg(const float* __restrict__ up,
                                                const float* __restrict__ Y,
                                                const float* __restrict__ Rw,
                                                const int* __restrict__ ei,
                                                const int* __restrict__ row_ptr,
                                                const int* __restrict__ perm,
                                                const float* __restrict__ Wcg,
                                                float* __restrict__ agg) {
    __shared__ float lWs[4096];        // s-major: lWs[s*256 + a*16 + t] = Wcg[a,s,t]
    __shared__ float lC[4][2][256];    // per-wave double-buffered C[a][t]

    int tid = threadIdx.x;
    for (int j = tid; j < 4096; j += 256) {
        int a = j >> 8, s = (j >> 4) & 15, t = j & 15;
        lWs[s*256 + a*16 + t] = Wcg[j];
    }
    __syncthreads();

    int wave = tid >> 6;
    int lane = tid & 63;
    int n = blockIdx.x * 4 + wave;
    int k0 = lane & 15;                // channel (and +16)
    int tq = lane >> 4;                // t-quad 0..3
    float* lCa = &lC[wave][0][0];
    float* lCb = &lC[wave][1][0];

    int start = row_ptr[n], end = row_ptr[n+1];
    float4 acc0 = {0,0,0,0}, acc1 = {0,0,0,0};

    if (start < end) {
        // ---- prologue: load edge `start` fully ----
        int e0 = perm[start];
        int s0 = ei[e0];
        const float4* Y4 = (const float4*)(Y + (size_t)e0*16);
        float4 ya = Y4[0], yb = Y4[1], yc = Y4[2], yd = Y4[3];
        float yv[16] = {ya.x,ya.y,ya.z,ya.w, yb.x,yb.y,yb.z,yb.w,
                        yc.x,yc.y,yc.z,yc.w, yd.x,yd.y,yd.z,yd.w};
        float rw0 = Rw[(size_t)e0*32 + k0];
        float rw1 = Rw[(size_t)e0*32 + k0 + 16];
        float4 u0 = *(const float4*)(up + (size_t)s0*512 + k0*16 + tq*4);
        float4 u1 = *(const float4*)(up + (size_t)s0*512 + (k0+16)*16 + tq*4);

        for (int ii = start; ii < end; ++ii) {
            // ---- phase A: C[a][t] for current edge -> lCa ----
            float4 c = {0,0,0,0};
#pragma unroll
            for (int s = 0; s < 16; ++s) {
                float4 w = *((const float4*)(lWs + s*256 + lane*4));
                c.x += yv[s]*w.x; c.y += yv[s]*w.y; c.z += yv[s]*w.z; c.w += yv[s]*w.w;
            }
            *((float4*)(lCa + lane*4)) = c;

            // ---- phase B: prefetch next edge (indices + data) ----
            int ii1 = (ii + 1 < end) ? ii + 1 : ii;
            int e_n = perm[ii1];
            int s_n = ei[e_n];
            const float4* Yn = (const float4*)(Y + (size_t)e_n*16);
            float4 nya = Yn[0], nyb = Yn[1], nyc = Yn[2], nyd = Yn[3];
            float nrw0 = Rw[(size_t)e_n*32 + k0];
            float nrw1 = Rw[(size_t)e_n*32 + k0 + 16];
            float4 nu0 = *(const float4*)(up + (size_t)s_n*512 + k0*16 + tq*4);
            float4 nu1 = *(const float4*)(up + (size_t)s_n*512 + (k0+16)*16 + tq*4);

            WAVE_SYNC();   // C writes visible

            // ---- phase C: msg; up row via shfl_xor quarters, scaled by Rw ----
            float4 su0 = make_float4(u0.x*rw0, u0.y*rw0, u0.z*rw0, u0.w*rw0);
            float4 su1 = make_float4(u1.x*rw1, u1.y*rw1, u1.z*rw1, u1.w*rw1);
#pragma unroll
            for (int m = 0; m < 4; ++m) {
                float4 a0 = (m == 0) ? su0 : shfl_xor4(su0, m << 4);
                float4 a1 = (m == 0) ? su1 : shfl_xor4(su1, m << 4);
                int aq = (tq ^ m) * 4;   // base a-index of this quarter
                float av[4] = {a0.x, a0.y, a0.z, a0.w};
                float bv[4] = {a1.x, a1.y, a1.z, a1.w};
#pragma unroll
                for (int j = 0; j < 4; ++j) {
                    float4 cv = *((const float4*)(lCa + (aq + j)*16 + tq*4));
                    acc0.x += av[j]*cv.x; acc0.y += av[j]*cv.y;
                    acc0.z += av[j]*cv.z; acc0.w += av[j]*cv.w;
                    acc1.x += bv[j]*cv.x; acc1.y += bv[j]*cv.y;
                    acc1.z += bv[j]*cv.z; acc1.w += bv[j]*cv.w;
                }
            }

            // ---- rotate: next -> cur; swap C buffers ----
#pragma unroll
            for (int s = 0; s < 4; ++s) { }
            yv[0]=nya.x; yv[1]=nya.y; yv[2]=nya.z; yv[3]=nya.w;
            yv[4]=nyb.x; yv[5]=nyb.y; yv[6]=nyb.z; yv[7]=nyb.w;
            yv[8]=nyc.x; yv[9]=nyc.y; yv[10]=nyc.z; yv[11]=nyc.w;
            yv[12]=nyd.x; yv[13]=nyd.y; yv[14]=nyd.z; yv[15]=nyd.w;
            rw0 = nrw0; rw1 = nrw1; u0 = nu0; u1 = nu1;
            float* t = lCa; lCa = lCb; lCb = t;
        }
    }

    float* o0 = agg + (size_t)n*512 + k0*16 + tq*4;
    float* o1 = agg + (size_t)n*512 + (k0+16)*16 + tq*4;
    *(float4*)o0 = make_float4(acc0.x*0.0625f, acc0.y*0.0625f, acc0.z*0.0625f, acc0.w*0.0625f);
    *(float4*)o1 = make_float4(acc1.x*0.0625f, acc1.y*0.0625f, acc1.z*0.0625f, acc1.w*0.0625f);
}

// ---------------- node update: channel-per-lane; 8 nodes/block ----------------
__global__ __launch_bounds__(256, 2) void k_node(const float* __restrict__ agg,
                                                 float* __restrict__ feats,
                                                 const int* __restrict__ spec,
                                                 const float* __restrict__ Wlin,
                                                 const float* __restrict__ Wskip,
                                                 const float* __restrict__ Wprod,
                                                 const float* __restrict__ Wcg2,
                                                 float* __restrict__ out,
                                                 int layer) {
    __shared__ float lWcg2[4096];
    __shared__ float lWlin[1024];
    __shared__ float lWprod[1024];
    __shared__ float lagg[4096];     // 8 nodes x 512, reused as s = mid+quad
    __shared__ float lmid[4352];     // 8 nodes x (32 rows padded to 17)

    int tid = threadIdx.x;
    int nbase = blockIdx.x * 8;
    for (int j = tid; j < 4096; j += 256) lWcg2[j] = Wcg2[j];
    for (int j = tid; j < 1024; j += 256) { lWlin[j] = Wlin[j]; lWprod[j] = Wprod[j]; }
    {
        const float4* src = (const float4*)(agg + (size_t)nbase*512);
        float4* dst = (float4*)lagg;
        for (int j = tid; j < 1024; j += 256) dst[j] = src[j];
    }
    __syncthreads();

    int lane = tid & 63;
    int wave = tid >> 6;
    int c = lane & 31;
    int node = wave*2 + (lane >> 5);
    int n = nbase + node;
    const float* la = lagg + node*512;

    // ---- mid[c][t] = sum_k agg[k][t] * Wlin[k][c] ----
    float m[16];
#pragma unroll
    for (int t = 0; t < 16; ++t) m[t] = 0.0f;
    for (int k = 0; k < 32; ++k) {
        float w = lWlin[k*32 + c];
        const float4* ar = (const float4*)(la + k*16);
        float4 a0 = ar[0], a1 = ar[1], a2 = ar[2], a3 = ar[3];
        m[0]+=a0.x*w;  m[1]+=a0.y*w;  m[2]+=a0.z*w;  m[3]+=a0.w*w;
        m[4]+=a1.x*w;  m[5]+=a1.y*w;  m[6]+=a1.z*w;  m[7]+=a1.w*w;
        m[8]+=a2.x*w;  m[9]+=a2.y*w;  m[10]+=a2.z*w; m[11]+=a2.w*w;
        m[12]+=a3.x*w; m[13]+=a3.y*w; m[14]+=a3.z*w; m[15]+=a3.w*w;
    }

    float* lmidw = lmid + node*544 + c*17;
#pragma unroll
    for (int a = 0; a < 16; ++a) lmidw[a] = m[a];
    WAVE_SYNC();

    // ---- quad[c][t] = sum_{a,b} m[a]*m[b]*Wcg2[a,b,t] ----
    float q[16];
#pragma unroll
    for (int t = 0; t < 16; ++t) q[t] = 0.0f;
    for (int a = 0; a < 16; ++a) {
        float ma = lmidw[a];
        const float* wbase = lWcg2 + a*256;
#pragma unroll
        for (int b = 0; b < 16; ++b) {
            float p = ma * m[b];
            const float4* w4 = (const float4*)(wbase + b*16);
            float4 w0 = w4[0], w1 = w4[1], w2 = w4[2], w3 = w4[3];
            q[0]+=p*w0.x;  q[1]+=p*w0.y;  q[2]+=p*w0.z;  q[3]+=p*w0.w;
            q[4]+=p*w1.x;  q[5]+=p*w1.y;  q[6]+=p*w1.z;  q[7]+=p*w1.w;
            q[8]+=p*w2.x;  q[9]+=p*w2.y;  q[10]+=p*w2.z; q[11]+=p*w2.w;
            q[12]+=p*w3.x; q[13]+=p*w3.y; q[14]+=p*w3.z; q[15]+=p*w3.w;
        }
    }

    float* lsrow = lagg + node*512 + c*16;
#pragma unroll
    for (int tq = 0; tq < 4; ++tq)
        *((float4*)(lsrow + tq*4)) = make_float4(m[tq*4]+q[tq*4], m[tq*4+1]+q[tq*4+1],
                                                 m[tq*4+2]+q[tq*4+2], m[tq*4+3]+q[tq*4+3]);
    WAVE_SYNC();

    // ---- out[c][t] = sum_k s[k][t]*Wprod[k][c] + sum_k feats[k][t]*Wskip[sp][k][c] ----
    int sp = spec[n];
    const float* wsk = Wskip + (size_t)sp*1024;
    const float* ls_node = lagg + node*512;
    const float* fg = feats + (size_t)n*512;
    float acc[16];
#pragma unroll
    for (int t = 0; t < 16; ++t) acc[t] = 0.0f;
    for (int k = 0; k < 32; ++k) {
        float wp = lWprod[k*32 + c];
        float wv = wsk[k*32 + c];
        const float4* sr = (const float4*)(ls_node + k*16);
        float4 s0 = sr[0], s1 = sr[1], s2 = sr[2], s3 = sr[3];
        const float4* fr = (const float4*)(fg + k*16);
        float4 f0 = fr[0], f1 = fr[1], f2 = fr[2], f3 = fr[3];
        acc[0]+=s0.x*wp+f0.x*wv;  acc[1]+=s0.y*wp+f0.y*wv;
        acc[2]+=s0.z*wp+f0.z*wv;  acc[3]+=s0.w*wp+f0.w*wv;
        acc[4]+=s1.x*wp+f1.x*wv;  acc[5]+=s1.y*wp+f1.y*wv;
        acc[6]+=s1.z*wp+f1.z*wv;  acc[7]+=s1.w*wp+f1.w*wv;
        acc[8]+=s2.x*wp+f2.x*wv;  acc[9]+=s2.y*wp+f2.y*wv;
        acc[10]+=s2.z*wp+f2.z*wv; acc[11]+=s2.w*wp+f2.w*wv;
        acc[12]+=s3.x*wp+f3.x*wv; acc[13]+=s3.y*wp+f3.y*wv;
        acc[14]+=s3.z*wp+f3.z*wv; acc[15]+=s3.w*wp+f3.w*wv;
    }
    float* fo = feats + (size_t)n*512 + c*16;
#pragma unroll
    for (int tq = 0; tq < 4; ++tq)
        *((float4*)(fo + tq*4)) = make_float4(acc[tq*4], acc[tq*4+1], acc[tq*4+2], acc[tq*4+3]);
    out[(size_t)n*(NL*K) + layer*K + c] = acc[0];
}

extern "C" void kernel_launch(void* const* d_in, const int* in_sizes, int n_in,
                              void* d_out, int out_size, void* d_ws, size_t ws_size,
                              hipStream_t stream) {
    const float* pos     = (const float*)d_in[0];
    const float* shifts  = (const float*)d_in[1];
    const float* attrs   = (const float*)d_in[2];
    const float* W_embed = (const float*)d_in[3];
    const float* W_up    = (const float*)d_in[4];
    const float* W_r1    = (const float*)d_in[5];
    const float* W_r2    = (const float*)d_in[6];
    const float* W_lin   = (const float*)d_in[7];
    const float* W_skip  = (const float*)d_in[8];
    const float* W_prod  = (const float*)d_in[9];
    const float* Wcg     = (const float*)d_in[10];
    const float* Wcg2    = (const float*)d_in[11];
    const int*   ei      = (const int*)d_in[12];
    float* out = (float*)d_out;

    uint8_t* p = (uint8_t*)d_ws;
    auto alloc = [&](size_t bytes) -> void* {
        void* r = (void*)p;
        p += (bytes + 255) & ~size_t(255);
        return r;
    };
    float* Y      = (float*)alloc((size_t)N_EDGES * 16 * sizeof(float));
    float* ef     = (float*)alloc((size_t)N_EDGES * 8  * sizeof(float));
    float* Rw     = (float*)alloc((size_t)N_EDGES * K  * sizeof(float));
    float* feats  = (float*)alloc((size_t)N_NODES * K * LDIM * sizeof(float));
    float* up     = (float*)alloc((size_t)N_NODES * K * LDIM * sizeof(float));
    float* agg    = (float*)alloc((size_t)N_NODES * K * LDIM * sizeof(float));
    int* counts   = (int*)alloc((size_t)N_NODES * sizeof(int));
    int* woff     = (int*)alloc((size_t)N_NODES * sizeof(int));
    int* row_ptr  = (int*)alloc((size_t)(N_NODES + 1) * sizeof(int));
    int* perm     = (int*)alloc((size_t)N_EDGES * sizeof(int));
    int* spec     = (int*)alloc((size_t)N_NODES * sizeof(int));

    hipMemsetAsync(counts, 0, N_NODES * sizeof(int), stream);
    k_geom<<<(N_EDGES + 255) / 256, 256, 0, stream>>>(pos, shifts, ei, Y, ef, counts);
    k_scan<<<1, 1024, 0, stream>>>(counts, row_ptr, woff);
    k_scatter<<<(N_EDGES + 255) / 256, 256, 0, stream>>>(ei, woff, perm);
    k_embed<<<(N_NODES * K + 255) / 256, 256, 0, stream>>>(attrs, W_embed, feats, spec);

    for (int i = 0; i < NL; i++) {
        k_up<<<N_NODES, 256, 0, stream>>>(feats, W_up + (size_t)i*K*K, up);
        k_radial<<<N_EDGES/256, 256, 0, stream>>>(ef, W_r1 + (size_t)i*NB*NH, W_r2 + (size_t)i*NH*K, Rw);
        k_agg<<<N_NODES/4, 256, 0, stream>>>(up, Y, Rw, ei, row_ptr, perm, Wcg, agg);
        k_node<<<N_NODES/8, 256, 0, stream>>>(agg, feats, spec,
                                              W_lin + (size_t)i*K*K, W_skip + (size_t)i*NZ*K*K,
                                              W_prod + (size_t)i*K*K, Wcg2, out, i);
    }
}